// Round 12
// baseline (172.300 us; speedup 1.0000x reference)
//
#include <hip/hip_runtime.h>
#include <math.h>

#define TEMP_INV (1.0f / 0.07f)
#define WEIGHT 0.5f
#define EPS 1e-8f
#define BB 64
#define TT 512
#define DD 512
#define RR 4                 // rows per chunk (4 KB batches — pipeline-preserving, R10/R11 lesson)
#define NC 2                 // chunks per wave -> 8 rows/wave, 2048 blocks
#define ROWS_PER_WAVE (RR * NC)

typedef float f32x4 __attribute__((ext_vector_type(4)));

__device__ inline float wave_sum(float v) {
    for (int o = 32; o >= 1; o >>= 1) v += __shfl_xor(v, o, 64);
    return v;
}
__device__ inline int wave_max_i(int v) {
    for (int o = 32; o >= 1; o >>= 1) v = max(v, __shfl_xor(v, o, 64));
    return v;
}
__device__ inline int wave_min_i(int v) {
    for (int o = 32; o >= 1; o >>= 1) v = min(v, __shfl_xor(v, o, 64));
    return v;
}

// One block (256 threads) per batch element b (unchanged, proven).
__global__ __launch_bounds__(256) void prep_kernel(
    const float* __restrict__ video, const float* __restrict__ audio,
    const int* __restrict__ mask,
    float* __restrict__ a_anchor, float* __restrict__ v_anchor,
    float* __restrict__ pos, float* __restrict__ neg, int* __restrict__ idx_out)
{
    const int b = blockIdx.x;
    const int tid = threadIdx.x;
    const int wid = tid >> 6, lane = tid & 63;
    __shared__ int sh_i[4];
    __shared__ float sh_f[4][3];
    __shared__ int s_idx;
    __shared__ float s_inva, s_invv;

    int m0 = mask[b * TT + tid];
    int m1 = mask[b * TT + tid + 256];
    int vmax = wave_max_i(max(m0, m1));
    if (lane == 0) sh_i[wid] = vmax;
    __syncthreads();
    if (tid == 0) {
        int r = sh_i[0];
        for (int i = 1; i < 4; i++) r = max(r, sh_i[i]);
        sh_i[0] = r;
    }
    __syncthreads();
    vmax = sh_i[0];
    __syncthreads();
    int cand = (m0 == vmax) ? tid : 0x7fffffff;
    int cand1 = (m1 == vmax) ? (tid + 256) : 0x7fffffff;
    cand = min(cand, cand1);
    cand = wave_min_i(cand);
    if (lane == 0) sh_i[wid] = cand;
    __syncthreads();
    if (tid == 0) {
        int r = sh_i[0];
        for (int i = 1; i < 4; i++) r = min(r, sh_i[i]);
        s_idx = r;
    }
    __syncthreads();
    const int idx = s_idx;

    const float* arow = audio + ((size_t)(b * TT + idx)) * DD;
    const float* vrow = video + ((size_t)(b * TT + idx)) * DD;
    float a0 = arow[tid], a1 = arow[tid + 256];
    float v0 = vrow[tid], v1 = vrow[tid + 256];
    float ssa = a0 * a0 + a1 * a1;
    float ssv = v0 * v0 + v1 * v1;
    float dav = a0 * v0 + a1 * v1;
    ssa = wave_sum(ssa);
    ssv = wave_sum(ssv);
    dav = wave_sum(dav);
    if (lane == 0) { sh_f[wid][0] = ssa; sh_f[wid][1] = ssv; sh_f[wid][2] = dav; }
    __syncthreads();
    if (tid == 0) {
        float ra = 0.f, rv = 0.f, rd = 0.f;
        for (int i = 0; i < 4; i++) { ra += sh_f[i][0]; rv += sh_f[i][1]; rd += sh_f[i][2]; }
        float inva = 1.0f / fmaxf(sqrtf(ra), EPS);
        float invv = 1.0f / fmaxf(sqrtf(rv), EPS);
        s_inva = inva; s_invv = invv;
        pos[b] = rd * inva * invv * TEMP_INV;
        neg[b] = 0.0f;
        neg[BB + b] = 0.0f;
        idx_out[b] = idx;
    }
    __syncthreads();
    const float inva = s_inva, invv = s_invv;
    a_anchor[b * DD + tid] = a0 * inva;
    a_anchor[b * DD + tid + 256] = a1 * inva;
    v_anchor[b * DD + tid] = v0 * invv;
    v_anchor[b * DD + tid + 256] = v1 * invv;
}

#define LOADC(B0, B1, CH)                                                   \
    _Pragma("unroll")                                                       \
    for (int r = 0; r < RR; r++) {                                          \
        const float* row_ = base + (size_t)(t0 + (CH) * RR + r) * DD;       \
        B0[r] = *(const f32x4*)(row_ + lane * 4);                           \
        B1[r] = *(const f32x4*)(row_ + 256 + lane * 4);                     \
    }

#define COMPC(B0, B1, CH)                                                   \
    _Pragma("unroll")                                                       \
    for (int r = 0; r < RR; r++) {                                          \
        const int k_ = (CH) * RR + r;                                       \
        dot[k_] = B0[r].x * c0.x + B0[r].y * c0.y + B0[r].z * c0.z          \
                + B0[r].w * c0.w + B1[r].x * c1.x + B1[r].y * c1.y          \
                + B1[r].z * c1.z + B1[r].w * c1.w;                          \
        nrm[k_] = B0[r].x * B0[r].x + B0[r].y * B0[r].y + B0[r].z * B0[r].z \
                + B0[r].w * B0[r].w + B1[r].x * B1[r].x + B1[r].y * B1[r].y \
                + B1[r].z * B1[r].z + B1[r].w * B1[r].w;                    \
    }

// grid (T/32, B, 2) = 2048 blocks, 8192 waves (8 blocks/CU).
// R10's proven ping-pong pipeline at RR=4 (4 KB chunks — the size that
// keeps buffers live in VGPRs; RR=2 collapsed to VGPR=32 and regressed),
// with NC=2 to double block count / TLP vs R10. Butterflies deferred to
// one batched end-reduction. No forced drains (R3/R4/R6/R8 lesson).
__global__ __launch_bounds__(256) void sims_kernel(
    const float* __restrict__ video, const float* __restrict__ audio,
    const float* __restrict__ a_anchor, const float* __restrict__ v_anchor,
    const int* __restrict__ idx_arr, float* __restrict__ neg)
{
    const int b = blockIdx.y;
    const int dir = blockIdx.z;
    const int wid = threadIdx.x >> 6, lane = threadIdx.x & 63;
    const int t0 = blockIdx.x * (4 * ROWS_PER_WAVE) + wid * ROWS_PER_WAVE;

    const float* base = (dir == 0 ? video : audio) + (size_t)b * TT * DD;
    const float* anc = (dir == 0 ? a_anchor : v_anchor) + b * DD;

    f32x4 c0 = *(const f32x4*)(anc + lane * 4);
    f32x4 c1 = *(const f32x4*)(anc + 256 + lane * 4);

    f32x4 pa0[RR], pa1[RR], pb0[RR], pb1[RR];
    float dot[ROWS_PER_WAVE], nrm[ROWS_PER_WAVE];

    LOADC(pa0, pa1, 0)          // chunk 0 in flight
    LOADC(pb0, pb1, 1)          // chunk 1 in flight
    COMPC(pa0, pa1, 0)          // consume 0 (waits vmcnt for batch 0 only)
    COMPC(pb0, pb1, 1)          // consume 1

    // one batched butterfly: 6 levels x 16 independent shfl-adds
#pragma unroll
    for (int o = 32; o >= 1; o >>= 1) {
#pragma unroll
        for (int k = 0; k < ROWS_PER_WAVE; k++) {
            dot[k] += __shfl_xor(dot[k], o, 64);
            nrm[k] += __shfl_xor(nrm[k], o, 64);
        }
    }

    if (lane == 0) {
        const int idx = idx_arr[b];
        float local = 0.0f;
#pragma unroll
        for (int k = 0; k < ROWS_PER_WAVE; k++) {
            const int t = t0 + k;
            float sim = dot[k] / fmaxf(sqrtf(nrm[k]), EPS) * TEMP_INV;
            local += (t == idx) ? 0.0f : expf(sim);
        }
        atomicAdd(&neg[dir * BB + b], local);
    }
}

__global__ void finalize_kernel(const float* __restrict__ pos,
                                const float* __restrict__ neg,
                                float* __restrict__ out)
{
    const int b = threadIdx.x;  // 64 threads, one wave
    float term = WEIGHT * (logf(neg[b]) + logf(neg[BB + b])) - pos[b];
    term = wave_sum(term);
    if (b == 0) out[0] = term / (float)BB;
}

extern "C" void kernel_launch(void* const* d_in, const int* in_sizes, int n_in,
                              void* d_out, int out_size, void* d_ws, size_t ws_size,
                              hipStream_t stream)
{
    const float* video = (const float*)d_in[0];
    const float* audio = (const float*)d_in[1];
    const int* mask = (const int*)d_in[2];

    float* ws = (float*)d_ws;
    float* a_anchor = ws;                 // B*D
    float* v_anchor = ws + BB * DD;       // B*D
    float* pos = ws + 2 * BB * DD;        // B
    float* neg = pos + BB;                // 2*B
    int* idx = (int*)(neg + 2 * BB);      // B

    prep_kernel<<<BB, 256, 0, stream>>>(video, audio, mask, a_anchor, v_anchor, pos, neg, idx);
    dim3 grid(TT / (4 * ROWS_PER_WAVE), BB, 2);
    sims_kernel<<<grid, 256, 0, stream>>>(video, audio, a_anchor, v_anchor, idx, neg);
    finalize_kernel<<<1, 64, 0, stream>>>(pos, neg, (float*)d_out);
}

// Round 13
// 156.515 us; speedup vs baseline: 1.1009x; 1.1009x over previous
//
#include <hip/hip_runtime.h>
#include <math.h>

#define TEMP_INV (1.0f / 0.07f)
#define WEIGHT 0.5f
#define EPS 1e-8f
#define BB 64
#define TT 512
#define DD 512
#define RR 4                 // rows per chunk
#define NC 4                 // chunks per wave -> 16 rows/wave
#define ROWS_PER_WAVE (RR * NC)
// DO NOT retune RR/NC: RR4xNC4 is the ONLY config where the compiler keeps
// the ping-pong buffers live (VGPR 44, 52.6 us). RR2xNC4 and RR4xNC2 both
// collapse to VGPR 32 / serialized loads and regress 12-20% (R11, R12).

typedef float f32x4 __attribute__((ext_vector_type(4)));

__device__ inline float wave_sum(float v) {
    for (int o = 32; o >= 1; o >>= 1) v += __shfl_xor(v, o, 64);
    return v;
}
__device__ inline int wave_max_i(int v) {
    for (int o = 32; o >= 1; o >>= 1) v = max(v, __shfl_xor(v, o, 64));
    return v;
}
__device__ inline int wave_min_i(int v) {
    for (int o = 32; o >= 1; o >>= 1) v = min(v, __shfl_xor(v, o, 64));
    return v;
}

// One block (256 threads) per batch element b (unchanged, proven).
__global__ __launch_bounds__(256) void prep_kernel(
    const float* __restrict__ video, const float* __restrict__ audio,
    const int* __restrict__ mask,
    float* __restrict__ a_anchor, float* __restrict__ v_anchor,
    float* __restrict__ pos, float* __restrict__ neg, int* __restrict__ idx_out)
{
    const int b = blockIdx.x;
    const int tid = threadIdx.x;
    const int wid = tid >> 6, lane = tid & 63;
    __shared__ int sh_i[4];
    __shared__ float sh_f[4][3];
    __shared__ int s_idx;
    __shared__ float s_inva, s_invv;

    int m0 = mask[b * TT + tid];
    int m1 = mask[b * TT + tid + 256];
    int vmax = wave_max_i(max(m0, m1));
    if (lane == 0) sh_i[wid] = vmax;
    __syncthreads();
    if (tid == 0) {
        int r = sh_i[0];
        for (int i = 1; i < 4; i++) r = max(r, sh_i[i]);
        sh_i[0] = r;
    }
    __syncthreads();
    vmax = sh_i[0];
    __syncthreads();
    int cand = (m0 == vmax) ? tid : 0x7fffffff;
    int cand1 = (m1 == vmax) ? (tid + 256) : 0x7fffffff;
    cand = min(cand, cand1);
    cand = wave_min_i(cand);
    if (lane == 0) sh_i[wid] = cand;
    __syncthreads();
    if (tid == 0) {
        int r = sh_i[0];
        for (int i = 1; i < 4; i++) r = min(r, sh_i[i]);
        s_idx = r;
    }
    __syncthreads();
    const int idx = s_idx;

    const float* arow = audio + ((size_t)(b * TT + idx)) * DD;
    const float* vrow = video + ((size_t)(b * TT + idx)) * DD;
    float a0 = arow[tid], a1 = arow[tid + 256];
    float v0 = vrow[tid], v1 = vrow[tid + 256];
    float ssa = a0 * a0 + a1 * a1;
    float ssv = v0 * v0 + v1 * v1;
    float dav = a0 * v0 + a1 * v1;
    ssa = wave_sum(ssa);
    ssv = wave_sum(ssv);
    dav = wave_sum(dav);
    if (lane == 0) { sh_f[wid][0] = ssa; sh_f[wid][1] = ssv; sh_f[wid][2] = dav; }
    __syncthreads();
    if (tid == 0) {
        float ra = 0.f, rv = 0.f, rd = 0.f;
        for (int i = 0; i < 4; i++) { ra += sh_f[i][0]; rv += sh_f[i][1]; rd += sh_f[i][2]; }
        float inva = 1.0f / fmaxf(sqrtf(ra), EPS);
        float invv = 1.0f / fmaxf(sqrtf(rv), EPS);
        s_inva = inva; s_invv = invv;
        pos[b] = rd * inva * invv * TEMP_INV;
        neg[b] = 0.0f;
        neg[BB + b] = 0.0f;
        idx_out[b] = idx;
    }
    __syncthreads();
    const float inva = s_inva, invv = s_invv;
    a_anchor[b * DD + tid] = a0 * inva;
    a_anchor[b * DD + tid + 256] = a1 * inva;
    v_anchor[b * DD + tid] = v0 * invv;
    v_anchor[b * DD + tid + 256] = v1 * invv;
}

#define LOADC(B0, B1, CH)                                                   \
    _Pragma("unroll")                                                       \
    for (int r = 0; r < RR; r++) {                                          \
        const float* row_ = base + (size_t)(t0 + (CH) * RR + r) * DD;       \
        B0[r] = *(const f32x4*)(row_ + lane * 4);                           \
        B1[r] = *(const f32x4*)(row_ + 256 + lane * 4);                     \
    }

#define COMPC(B0, B1, CH)                                                   \
    _Pragma("unroll")                                                       \
    for (int r = 0; r < RR; r++) {                                          \
        const int k_ = (CH) * RR + r;                                       \
        dot[k_] = B0[r].x * c0.x + B0[r].y * c0.y + B0[r].z * c0.z          \
                + B0[r].w * c0.w + B1[r].x * c1.x + B1[r].y * c1.y          \
                + B1[r].z * c1.z + B1[r].w * c1.w;                          \
        nrm[k_] = B0[r].x * B0[r].x + B0[r].y * B0[r].y + B0[r].z * B0[r].z \
                + B0[r].w * B0[r].w + B1[r].x * B1[r].x + B1[r].y * B1[r].y \
                + B1[r].z * B1[r].z + B1[r].w * B1[r].w;                    \
    }

// grid (T/64, B, 2) = 1024 blocks, 4096 waves (all device-resident).
// R10 EXACT: software-pipelined ping-pong chunk buffers, loads of chunk
// i+1 before compute of chunk i; compiler's fine-grained vmcnt keeps one
// 8 KB batch in flight through every compute phase. All butterflies
// deferred to one batched 32-value end-reduction. No forced drains
// (sched_barrier / LDS-DMA / asm vmcnt(0) / fence-ticket all regressed
// to 100-147 us). Measured: sims 52.6 us, demand 2.55 TB/s — the top of
// the six-structure plateau (2.1-2.6 TB/s) for this streaming pattern.
__global__ __launch_bounds__(256) void sims_kernel(
    const float* __restrict__ video, const float* __restrict__ audio,
    const float* __restrict__ a_anchor, const float* __restrict__ v_anchor,
    const int* __restrict__ idx_arr, float* __restrict__ neg)
{
    const int b = blockIdx.y;
    const int dir = blockIdx.z;
    const int wid = threadIdx.x >> 6, lane = threadIdx.x & 63;
    const int t0 = blockIdx.x * (4 * ROWS_PER_WAVE) + wid * ROWS_PER_WAVE;

    const float* base = (dir == 0 ? video : audio) + (size_t)b * TT * DD;
    const float* anc = (dir == 0 ? a_anchor : v_anchor) + b * DD;

    f32x4 c0 = *(const f32x4*)(anc + lane * 4);
    f32x4 c1 = *(const f32x4*)(anc + 256 + lane * 4);

    f32x4 pa0[RR], pa1[RR], pb0[RR], pb1[RR];
    float dot[ROWS_PER_WAVE], nrm[ROWS_PER_WAVE];

    LOADC(pa0, pa1, 0)          // chunk 0 in flight
    LOADC(pb0, pb1, 1)          // chunk 1 in flight
    COMPC(pa0, pa1, 0)          // consume 0 (waits vmcnt for batch 0 only)
    LOADC(pa0, pa1, 2)          // chunk 2 in flight
    COMPC(pb0, pb1, 1)          // consume 1
    LOADC(pb0, pb1, 3)          // chunk 3 in flight
    COMPC(pa0, pa1, 2)          // consume 2
    COMPC(pb0, pb1, 3)          // consume 3

    // one batched butterfly: 6 levels x 32 independent shfl-adds
#pragma unroll
    for (int o = 32; o >= 1; o >>= 1) {
#pragma unroll
        for (int k = 0; k < ROWS_PER_WAVE; k++) {
            dot[k] += __shfl_xor(dot[k], o, 64);
            nrm[k] += __shfl_xor(nrm[k], o, 64);
        }
    }

    if (lane == 0) {
        const int idx = idx_arr[b];
        float local = 0.0f;
#pragma unroll
        for (int k = 0; k < ROWS_PER_WAVE; k++) {
            const int t = t0 + k;
            float sim = dot[k] / fmaxf(sqrtf(nrm[k]), EPS) * TEMP_INV;
            local += (t == idx) ? 0.0f : expf(sim);
        }
        atomicAdd(&neg[dir * BB + b], local);
    }
}

__global__ void finalize_kernel(const float* __restrict__ pos,
                                const float* __restrict__ neg,
                                float* __restrict__ out)
{
    const int b = threadIdx.x;  // 64 threads, one wave
    float term = WEIGHT * (logf(neg[b]) + logf(neg[BB + b])) - pos[b];
    term = wave_sum(term);
    if (b == 0) out[0] = term / (float)BB;
}

extern "C" void kernel_launch(void* const* d_in, const int* in_sizes, int n_in,
                              void* d_out, int out_size, void* d_ws, size_t ws_size,
                              hipStream_t stream)
{
    const float* video = (const float*)d_in[0];
    const float* audio = (const float*)d_in[1];
    const int* mask = (const int*)d_in[2];

    float* ws = (float*)d_ws;
    float* a_anchor = ws;                 // B*D
    float* v_anchor = ws + BB * DD;       // B*D
    float* pos = ws + 2 * BB * DD;        // B
    float* neg = pos + BB;                // 2*B
    int* idx = (int*)(neg + 2 * BB);      // B

    prep_kernel<<<BB, 256, 0, stream>>>(video, audio, mask, a_anchor, v_anchor, pos, neg, idx);
    dim3 grid(TT / (4 * ROWS_PER_WAVE), BB, 2);
    sims_kernel<<<grid, 256, 0, stream>>>(video, audio, a_anchor, v_anchor, idx, neg);
    finalize_kernel<<<1, 64, 0, stream>>>(pos, neg, (float*)d_out);
}